// Round 5
// baseline (1289.642 us; speedup 1.0000x reference)
//
#include <hip/hip_runtime.h>
#include <math.h>

#define B_ 4
#define H_ 16
#define S_ 1024
#define R_ 512
#define BQ 32
#define BK 32
#define NTHREADS 512

typedef unsigned short u16;
typedef unsigned int   u32;
typedef short bf16x8 __attribute__((ext_vector_type(8)));
typedef float f32x4  __attribute__((ext_vector_type(4)));

__device__ inline u16 f2bf(float x) {
    union { float f; u32 u; } v; v.f = x;
    return (u16)((v.u + 0x7fffu + ((v.u >> 16) & 1u)) >> 16);
}
__device__ inline u32 pack2(float a, float b) {
    return (u32)f2bf(a) | ((u32)f2bf(b) << 16);
}

#define MFMA16(a, b, c) __builtin_amdgcn_mfma_f32_16x16x32_bf16(a, b, c, 0, 0, 0)

// async global->LDS, 16B per lane. LDS dest must be wave-uniform (HW adds lane*16).
__device__ inline void gload16(const void* g, void* l) {
    __builtin_amdgcn_global_load_lds(
        (const __attribute__((address_space(1))) void*)g,
        (__attribute__((address_space(3))) void*)l,
        16, 0, 0);
}

// barrier that does NOT drain vmcnt (keeps async prefetch in flight),
// but drains lgkm so LDS writes are visible across waves.
#define RAW_BARRIER() do {                                 \
    asm volatile("s_waitcnt lgkmcnt(0)" ::: "memory");     \
    __builtin_amdgcn_s_barrier();                          \
    asm volatile("" ::: "memory");                         \
} while (0)

// ---------------------------------------------------------------------------
// Prep kernel (verified round 1): ckv f32 -> bf16, two layouts:
//   ckv_bf [b][k][r]  16B chunks XOR-swizzled within each 128B span by (k&7)
//                     -> LINEAR global_load_lds yields conflict-free LDS tiles.
//   ckvT   [b][r][k]  plain transpose (consumed directly from global by mm2).
// ---------------------------------------------------------------------------
__global__ __launch_bounds__(256)
void mla_prep_kernel(const float* __restrict__ ckv,
                     u16* __restrict__ ckv_bf,
                     u16* __restrict__ ckvT)
{
    const int tid = threadIdx.x;
    const int k0 = blockIdx.x * 64;
    const int r0 = blockIdx.y * 64;
    const int b  = blockIdx.z;

    __shared__ u16 sT[64][72];   // [r_local][k_local], padded rows

    const float* src = ckv + ((size_t)b * S_ + k0) * R_ + r0;
    u16* obf = ckv_bf + ((size_t)b * S_ + k0) * R_ + r0;

    #pragma unroll
    for (int i = 0; i < 2; ++i) {
        int idx = tid + i * 256;          // 0..511
        int kk  = idx >> 3;               // 0..63 local k row
        int c8  = idx & 7;                // dest 16B chunk within 128B span
        int csrc = c8 ^ (kk & 7);         // source chunk (XOR swizzle)
        const float* p = src + (size_t)kk * R_ + csrc * 8;
        float4 f0 = *(const float4*)p;
        float4 f1 = *(const float4*)(p + 4);
        u32 w0 = pack2(f0.x, f0.y), w1 = pack2(f0.z, f0.w);
        u32 w2 = pack2(f1.x, f1.y), w3 = pack2(f1.z, f1.w);
        u32* dst = (u32*)(obf + (size_t)kk * R_ + c8 * 8);
        dst[0] = w0; dst[1] = w1; dst[2] = w2; dst[3] = w3;
        u16 e[8] = {(u16)w0,(u16)(w0>>16),(u16)w1,(u16)(w1>>16),
                    (u16)w2,(u16)(w2>>16),(u16)w3,(u16)(w3>>16)};
        #pragma unroll
        for (int j = 0; j < 8; ++j) sT[csrc * 8 + j][kk] = e[j];
    }
    __syncthreads();

    u16* obT = ckvT + (size_t)b * R_ * S_;
    #pragma unroll
    for (int i = 0; i < 2; ++i) {
        int idx = tid + i * 256;          // 0..511
        int rr = idx >> 3;                // 0..63 local r row
        int kc = idx & 7;                 // 16B chunk along k
        const u16* s = &sT[rr][kc * 8];
        u32* dd = (u32*)(obT + (size_t)(r0 + rr) * S_ + k0 + kc * 8);
        dd[0] = (u32)s[0] | ((u32)s[1] << 16);
        dd[1] = (u32)s[2] | ((u32)s[3] << 16);
        dd[2] = (u32)s[4] | ((u32)s[5] << 16);
        dd[3] = (u32)s[6] | ((u32)s[7] << 16);
    }
}

// ---------------------------------------------------------------------------
// Main kernel, "slim" decomposition for 2 blocks/CU (4 waves/SIMD):
//   BQ=32, 512 threads, 8 waves. mm1: wave (qg, ktg, kq) computes a 16x16
//   score sub-tile over K-half kq*256; partials combined via padded LDS.
//   mm2: wave (mi=qg, rq) computes 16 rows x 128 r-cols; B-frags straight
//   from global ckvT (L2-hot). Per-thread state: aq 32 + acc 32 regs.
//   LDS 77.6 KB. launch_bounds(512,4) pins the 128-VGPR tier.
//   Mask+causal folded into prefetched rope (-inf at load time).
// ---------------------------------------------------------------------------
__global__ __launch_bounds__(NTHREADS, 4)
void mla_attn_kernel(const float* __restrict__ qn,
                     const float* __restrict__ rope,
                     const int*   __restrict__ mask,
                     const int*   __restrict__ cmaskp,
                     const u16*   __restrict__ ckv_bf,
                     const u16*   __restrict__ ckvT,
                     float*       __restrict__ out)
{
    const int tid  = threadIdx.x;
    const int lane = tid & 63;
    const int wv   = tid >> 6;      // 0..7
    const int l15  = lane & 15;
    const int lq   = lane >> 4;     // 0..3
    const int qg   = wv >> 2;       // 0..1 : 16-row group (mm1 + mm2 rows)
    const int ktg  = (wv >> 1) & 1; // 0..1 : 16-kcol half (mm1)
    const int kq   = wv & 1;        // 0..1 : K-half 256 (mm1)
    const int rq   = wv & 3;        // 0..3 : 128-col quarter (mm2)
    const bool isSM = (kq == 0);    // softmax waves: wv 0,2,4,6
    const int sub  = ktg;           // softmax 8-row half within qg
    const int r8   = lane >> 3;     // 0..7 softmax row
    const int cg   = lane & 7;      // 0..7 softmax col group (4 cols)

    // heavy (high-qt, causal) blocks first
    const int qt = 31 - (int)blockIdx.x;
    const int h  = blockIdx.y;
    const int b  = blockIdx.z;
    const int q0 = qt * BQ;

    const int cflag = cmaskp[0];

    // LDS: 65536 + 9248 + 2560 + 128 + 128 = 77,600 B  -> 2 blocks/CU
    __shared__ __align__(16) u16   sCKV[2][BK][R_];      // swizzled 1024B rows
    __shared__ __align__(16) float sPart[2][2][32][17];  // [qg][kq][col][row16+pad]
    __shared__ __align__(16) u16   sP[BQ][40];           // P bf16, 80B rows
    __shared__ __align__(16) float sAlpha[BQ];
    __shared__ __align__(16) float sL[BQ];

    // ---- Q fragments: rows qg*16+l15, K-slice [kq*256, +256) -> 32 VGPRs ----
    bf16x8 aq[8];
    {
        const float* qrow = qn + ((size_t)((b * H_ + h) * S_ + q0 + qg * 16 + l15)) * R_
                          + kq * 256;
        #pragma unroll
        for (int s = 0; s < 8; ++s) {
            const float* p = qrow + 32 * s + lq * 8;
            float4 f0 = *(const float4*)p;
            float4 f1 = *(const float4*)(p + 4);
            union { u32 u[4]; bf16x8 v; } cv;
            cv.u[0] = pack2(f0.x, f0.y); cv.u[1] = pack2(f0.z, f0.w);
            cv.u[2] = pack2(f1.x, f1.y); cv.u[3] = pack2(f1.z, f1.w);
            aq[s] = cv.v;
        }
    }

    // mm2 accumulator: 16 rows (mi=qg) x 128 cols (rq) -> 8 x f32x4 = 32 regs
    f32x4 acc[8];
    #pragma unroll
    for (int i = 0; i < 8; ++i) acc[i] = (f32x4){0.f, 0.f, 0.f, 0.f};

    float m_run = -INFINITY, l_run = 0.0f;   // softmax waves only (1 row/lane)

    const u16*   ckvb  = ckv_bf + (size_t)b * S_ * R_;
    const u16*   ckvTb = ckvT   + (size_t)b * R_ * S_;
    const float* ropeb = rope + ((size_t)(b * H_ + h)) * S_ * S_;
    const int*   maskb = mask + b * S_;

    const int nkt = cflag ? (qt + 1) : (S_ / BK);
    const float SCALE = 0.07216878364870323f;   // 1/sqrt(64+128)
    const int rowg = q0 + qg * 16 + sub * 8 + r8;   // softmax global row
    const int rowl = qg * 16 + sub * 8 + r8;        // softmax block row

    float rp0, rp1, rp2, rp3;   // rope (+mask+causal folded) for current tile

    // ---- prologue: stage tile 0, rope(0) ----
    {
        char* lA = (char*)&sCKV[0][0][0] + wv * 1024;
        const char* gA = (const char*)ckvb;
        #pragma unroll
        for (int rd = 0; rd < 4; ++rd)
            gload16(gA + (u32)(rd * 8192 + wv * 1024 + lane * 16), lA + rd * 8192);
        if (isSM) {
            const int cb = cg * 4;
            float4 rv = *(const float4*)(ropeb + (size_t)rowg * S_ + cb);
            int4   mv = *(const int4*)(maskb + cb);
            rp0 = (mv.x || (cflag && cb + 0 > rowg)) ? -INFINITY : rv.x;
            rp1 = (mv.y || (cflag && cb + 1 > rowg)) ? -INFINITY : rv.y;
            rp2 = (mv.z || (cflag && cb + 2 > rowg)) ? -INFINITY : rv.z;
            rp3 = (mv.w || (cflag && cb + 3 > rowg)) ? -INFINITY : rv.w;
        }
    }
    __syncthreads();   // tile 0 staged (vmcnt drained)

    for (int kt = 0; kt < nkt; ++kt) {
        const int d = kt & 1;
        const bool more = (kt + 1 < nkt);

        // ---- issue async stage(kt+1); rope(kt+1) prefetch (softmax waves) ----
        if (more) {
            const char* gA = (const char*)ckvb + (size_t)(kt + 1) * (BK * R_ * 2);
            char* lA = (char*)&sCKV[d ^ 1][0][0] + wv * 1024;
            #pragma unroll
            for (int rd = 0; rd < 4; ++rd)
                gload16(gA + (u32)(rd * 8192 + wv * 1024 + lane * 16), lA + rd * 8192);
        }
        float rn0, rn1, rn2, rn3;
        if (isSM && more) {
            const int cb = (kt + 1) * BK + cg * 4;
            float4 rv = *(const float4*)(ropeb + (size_t)rowg * S_ + cb);
            int4   mv = *(const int4*)(maskb + cb);
            rn0 = (mv.x || (cflag && cb + 0 > rowg)) ? -INFINITY : rv.x;
            rn1 = (mv.y || (cflag && cb + 1 > rowg)) ? -INFINITY : rv.y;
            rn2 = (mv.z || (cflag && cb + 2 > rowg)) ? -INFINITY : rv.z;
            rn3 = (mv.w || (cflag && cb + 3 > rowg)) ? -INFINITY : rv.w;
        }

        // ---- mm1: 16x16 score sub-tile over K-half (8 MFMA) ----
        {
            f32x4 sc = {0.f, 0.f, 0.f, 0.f};
            const char* base = (const char*)&sCKV[d][0][0];
            const u32 rowb = (u32)(ktg * 16 + l15) * 1024;
            const u32 swz  = ((u32)(l15 & 7)) << 4;
            __builtin_amdgcn_s_setprio(1);
            #pragma unroll
            for (int s = 0; s < 8; ++s) {
                u32 coff = ((u32)(kq * 512 + s * 64 + lq * 16)) ^ swz;
                bf16x8 bf = *(const bf16x8*)(base + rowb + coff);
                sc = MFMA16(aq[s], bf, sc);
            }
            __builtin_amdgcn_s_setprio(0);
            // partials: [qg][kq][col = ktg*16+l15][row = 4lq+reg], padded rows
            #pragma unroll
            for (int reg = 0; reg < 4; ++reg)
                sPart[qg][kq][ktg * 16 + l15][4 * lq + reg] = sc[reg];
        }

        RAW_BARRIER();   // B1: partials visible; stage stays in flight

        // ---- mm2 B-frag batch 1 issued here (in flight across softmax+B2) ----
        const u16* tb = ckvTb + (size_t)(rq * 128 + l15) * S_ + kt * BK + lq * 8;
        bf16x8 bfr0 = *(const bf16x8*)(tb);
        bf16x8 bfr1 = *(const bf16x8*)(tb + (size_t)16 * S_);
        bf16x8 bfr2 = *(const bf16x8*)(tb + (size_t)32 * S_);
        bf16x8 bfr3 = *(const bf16x8*)(tb + (size_t)48 * S_);

        // ---- softmax (waves 0,2,4,6): 8 rows x full 32 cols each ----
        if (isSM) {
            const int rl = sub * 8 + r8;    // row within qg (0..15)
            float s0, s1, s2, s3;
            {
                const int c = cg * 4;
                s0 = (sPart[qg][0][c + 0][rl] + sPart[qg][1][c + 0][rl] + rp0) * SCALE;
                s1 = (sPart[qg][0][c + 1][rl] + sPart[qg][1][c + 1][rl] + rp1) * SCALE;
                s2 = (sPart[qg][0][c + 2][rl] + sPart[qg][1][c + 2][rl] + rp2) * SCALE;
                s3 = (sPart[qg][0][c + 3][rl] + sPart[qg][1][c + 3][rl] + rp3) * SCALE;
            }
            float vm = fmaxf(fmaxf(s0, s1), fmaxf(s2, s3));
            vm = fmaxf(vm, __shfl_xor(vm, 1));
            vm = fmaxf(vm, __shfl_xor(vm, 2));
            vm = fmaxf(vm, __shfl_xor(vm, 4));
            float mn = fmaxf(m_run, vm);
            float alpha, p0, p1, p2, p3;
            if (mn == -INFINITY) {
                alpha = 1.0f; p0 = p1 = p2 = p3 = 0.0f;
            } else {
                alpha = __expf(m_run - mn);
                p0 = __expf(s0 - mn); p1 = __expf(s1 - mn);
                p2 = __expf(s2 - mn); p3 = __expf(s3 - mn);
            }
            float rs = (p0 + p1) + (p2 + p3);
            rs += __shfl_xor(rs, 1);
            rs += __shfl_xor(rs, 2);
            rs += __shfl_xor(rs, 4);
            m_run = mn;
            l_run = l_run * alpha + rs;
            u32* pw = (u32*)&sP[rowl][cg * 4];
            pw[0] = pack2(p0, p1);
            pw[1] = pack2(p2, p3);
            if (cg == 0) sAlpha[rowl] = alpha;
        }

        RAW_BARRIER();   // B2: P + alpha visible; stage + bfr batch1 in flight

        // ---- mm2: O = O*alpha + P . ckvT  (16 rows x 128 cols per wave) ----
        {
            // batch 2 issued first (latency covered by scale + batch-1 MFMAs)
            bf16x8 bfr4 = *(const bf16x8*)(tb + (size_t)64 * S_);
            bf16x8 bfr5 = *(const bf16x8*)(tb + (size_t)80 * S_);
            bf16x8 bfr6 = *(const bf16x8*)(tb + (size_t)96 * S_);
            bf16x8 bfr7 = *(const bf16x8*)(tb + (size_t)112 * S_);

            float alr0 = sAlpha[qg * 16 + 4 * lq + 0];
            float alr1 = sAlpha[qg * 16 + 4 * lq + 1];
            float alr2 = sAlpha[qg * 16 + 4 * lq + 2];
            float alr3 = sAlpha[qg * 16 + 4 * lq + 3];
            #pragma unroll
            for (int ni = 0; ni < 8; ++ni) {
                acc[ni][0] *= alr0; acc[ni][1] *= alr1;
                acc[ni][2] *= alr2; acc[ni][3] *= alr3;
            }
            bf16x8 af = *(const bf16x8*)&sP[qg * 16 + l15][lq * 8];
            __builtin_amdgcn_s_setprio(1);
            acc[0] = MFMA16(af, bfr0, acc[0]);
            acc[1] = MFMA16(af, bfr1, acc[1]);
            acc[2] = MFMA16(af, bfr2, acc[2]);
            acc[3] = MFMA16(af, bfr3, acc[3]);
            acc[4] = MFMA16(af, bfr4, acc[4]);
            acc[5] = MFMA16(af, bfr5, acc[5]);
            acc[6] = MFMA16(af, bfr6, acc[6]);
            acc[7] = MFMA16(af, bfr7, acc[7]);
            __builtin_amdgcn_s_setprio(0);
        }

        __syncthreads();   // B3: drains vmcnt -> tile kt+1 staged & visible

        if (isSM && more) { rp0 = rn0; rp1 = rn1; rp2 = rn2; rp3 = rn3; }
    }

    // ---- epilogue: publish l, then O / l ----
    if (isSM && cg == 0) sL[rowl] = l_run;
    __syncthreads();

    float* ob = out + ((size_t)((b * H_ + h) * S_ + q0)) * R_ + rq * 128;
    #pragma unroll
    for (int reg = 0; reg < 4; ++reg) {
        const int row = qg * 16 + 4 * lq + reg;
        const float linv = 1.0f / sL[row];
        #pragma unroll
        for (int ni = 0; ni < 8; ++ni)
            ob[(size_t)row * R_ + ni * 16 + l15] = acc[ni][reg] * linv;
    }
}

extern "C" void kernel_launch(void* const* d_in, const int* in_sizes, int n_in,
                              void* d_out, int out_size, void* d_ws, size_t ws_size,
                              hipStream_t stream)
{
    (void)in_sizes; (void)n_in; (void)out_size; (void)ws_size;
    const float* qn   = (const float*)d_in[0];
    const float* ckv  = (const float*)d_in[1];
    const float* rope = (const float*)d_in[2];
    const int*   mask = (const int*)d_in[3];
    const int*   cm   = (const int*)d_in[4];
    float* out = (float*)d_out;

    // workspace: ckv_bf (4MB, swizzled [b][k][r]) + ckvT (4MB, [b][r][k])
    u16* ckv_bf = (u16*)d_ws;
    u16* ckvT   = ckv_bf + (size_t)B_ * S_ * R_;

    hipLaunchKernelGGL(mla_prep_kernel, dim3(S_ / 64, R_ / 64, B_), dim3(256),
                       0, stream, ckv, ckv_bf, ckvT);
    hipLaunchKernelGGL(mla_attn_kernel, dim3(S_ / BQ, H_, B_), dim3(NTHREADS),
                       0, stream, qn, rope, mask, cm, ckv_bf, ckvT, out);
}